// Round 8
// baseline (118.075 us; speedup 1.0000x reference)
//
#include <hip/hip_runtime.h>
#include <hip/hip_bf16.h>

#define N_PIX 8192
#define C_DIM 128
#define HW 4096
// exp(dot/0.1) = exp2(dot * 14.42695...); fold sqrt of that into each vector.
#define PRESCALE 3.7982825f  // sqrt(log2(e)/0.1)
#define NUM_CLASSES 4

typedef __attribute__((ext_vector_type(8))) short short8;   // 8 x bf16 (4 VGPRs)
typedef __attribute__((ext_vector_type(4))) float float4v;  // 4 x f32 acc

// Fragment-linear layout (R7 win): ebfT[((T*4 + s)*64 + lane)*8 + j] = e[T*16 + lq][s*32 + quad*8 + j],
// lane = quad*16 + lq. Fragment load = base + lane*16B: one coalesced 1KB dwordx4.

// ---------------- Kernel 1: L2-normalize + prescale + bf16 cast into ebfT; zero pos/tot ----------------
__global__ __launch_bounds__(256) void normscale_kernel(const float* __restrict__ emb,
                                                        unsigned short* __restrict__ ebfT,
                                                        float* __restrict__ pz) {
    const int tid = threadIdx.x;
    const int p16 = tid & 15;   // pixel within tile (lq)
    const int g = tid >> 4;     // channel group 0..15 (8 channels each)
    const int n = blockIdx.x * 16 + p16;
    const int b = n >> 12;
    const int hw = n & (HW - 1);
    const float* base = emb + b * (C_DIM * HW) + hw;

    float v[8];
    float ss = 0.f;
#pragma unroll
    for (int i = 0; i < 8; ++i) {
        v[i] = base[(g * 8 + i) * HW];
        ss += v[i] * v[i];
    }
    ss += __shfl_xor(ss, 16, 64);
    ss += __shfl_xor(ss, 32, 64);
    __shared__ float red[4][16];
    const int wv = tid >> 6;
    if ((tid & 63) < 16) red[wv][p16] = ss;
    __syncthreads();
    float tot = red[0][p16] + red[1][p16] + red[2][p16] + red[3][p16];
    float inv = PRESCALE / fmaxf(sqrtf(tot), 1e-12f);

    unsigned short us[8];
#pragma unroll
    for (int i = 0; i < 8; ++i) {
        __hip_bfloat16 h = __float2bfloat16(v[i] * inv);
        us[i] = *reinterpret_cast<unsigned short*>(&h);
    }
    const int s = g >> 2, quad = g & 3;
    unsigned short* dst = ebfT + (((blockIdx.x * 4 + s) * 64 + quad * 16 + p16) << 3);
    *reinterpret_cast<short8*>(dst) = *reinterpret_cast<short8*>(us);

    if (blockIdx.x < 64) pz[blockIdx.x * 256 + tid] = 0.f;
}

// ---------------- Kernel 2: triangular fused S = e e^T, exp2, masked row+col sums ----------------
// Grid (64, 33): bi = I-panel (128 rows), d = panel shift; jp = (bi+d)%64 = J-panel.
// d=0: diagonal panel (full 128x128, row-side only, self-masked).
// d=1..31: each unordered panel pair exactly once. d=32: double-covered -> bi>=32 culled.
// Off-diagonal blocks use symmetry: each ex(i,j) feeds row-side (rows of bi) AND
// col-side (rows of jp, via LDS accumulator flushed once per block). ~0.51x the
// tile-work of R7. Lessons: (256,4) not (256,8) [R3]; plain cached loads, no
// global_load_lds [R5]; macros + constant-indexed arrays, no lambdas [R6].
__global__ __launch_bounds__(256, 4) void pairwise_kernel(const unsigned short* __restrict__ ebfT,
                                                          const int* __restrict__ lab,
                                                          float* __restrict__ pos,
                                                          float* __restrict__ tot) {
    const int bi = blockIdx.x;
    const int d = blockIdx.y;
    if (d == 32 && bi >= 32) return;  // wrap double-cover cull (block-uniform)
    const int jp = (bi + d) & 63;
    const int Ipanel = bi << 7;
    const int Jpanel = jp << 7;
    const bool offdiag = (d != 0);

    __shared__ float colT[128];
    __shared__ float colP[128];

    const int wave = threadIdx.x >> 6;
    const int lane = threadIdx.x & 63;
    const int quad = lane >> 4;
    const int lq = lane & 15;

    if (threadIdx.x < 128) {
        colT[threadIdx.x] = 0.f;
        colP[threadIdx.x] = 0.f;
    }

    const int I0 = Ipanel + wave * 32;

    // A fragments: tiles (I0>>4), (I0>>4)+1 — coalesced lane*16B loads.
    short8 afrag[2][4];
#pragma unroll
    for (int a = 0; a < 2; ++a) {
        const unsigned short* ab = ebfT + ((((I0 >> 4) + a) * 4) * 64 + lane) * 8;
#pragma unroll
        for (int s = 0; s < 4; ++s)
            afrag[a][s] = *reinterpret_cast<const short8*>(ab + s * 512);
    }
    int lab_row[2][4];
#pragma unroll
    for (int a = 0; a < 2; ++a)
#pragma unroll
        for (int r = 0; r < 4; ++r) lab_row[a][r] = lab[I0 + a * 16 + quad * 4 + r];

    float tacc[2][4] = {};
    float pacc[2][4] = {};

    if (offdiag) __syncthreads();  // colT/colP zeroed before any ds_add

#define EPILOGUE(A, ACC, MASKED, OFFD)                                      \
    {                                                                       \
        _Pragma("unroll") for (int r = 0; r < 4; ++r) {                     \
            float ex = __builtin_amdgcn_exp2f(ACC[r]);                      \
            if (MASKED) ex = (lq == quad * 4 + r) ? 0.f : ex;               \
            tacc[A][r] += ex;                                               \
            float pxe = (lab_row[A][r] == lab_col) ? ex : 0.f;              \
            pacc[A][r] += pxe;                                              \
            if (OFFD) { colTs += ex; colPs += pxe; }                        \
        }                                                                   \
    }

    const unsigned short* bbase = ebfT + ((Jpanel >> 4) * 4 * 64 + lane) * 8;

    for (int t = 0; t < 8; ++t) {
        const int J = Jpanel + t * 16;
        const int lab_col = lab[J + lq];
        const unsigned short* bt = bbase + t * 2048;
        short8 bfrag[4];
#pragma unroll
        for (int s = 0; s < 4; ++s)
            bfrag[s] = *reinterpret_cast<const short8*>(bt + s * 512);

        float4v acc0 = {0.f, 0.f, 0.f, 0.f};
        float4v acc1 = {0.f, 0.f, 0.f, 0.f};
#pragma unroll
        for (int s = 0; s < 4; ++s) {
            acc0 = __builtin_amdgcn_mfma_f32_16x16x32_bf16(afrag[0][s], bfrag[s], acc0, 0, 0, 0);
            acc1 = __builtin_amdgcn_mfma_f32_16x16x32_bf16(afrag[1][s], bfrag[s], acc1, 0, 0, 0);
        }

        float colTs = 0.f, colPs = 0.f;
        if (offdiag) {
            EPILOGUE(0, acc0, false, true)
            EPILOGUE(1, acc1, false, true)
            // col-side: sum over this wave's 32 rows -> butterfly over quads
            colTs += __shfl_xor(colTs, 16, 64);
            colTs += __shfl_xor(colTs, 32, 64);
            colPs += __shfl_xor(colPs, 16, 64);
            colPs += __shfl_xor(colPs, 32, 64);
            if (quad == 0) {
                atomicAdd(&colT[t * 16 + lq], colTs);
                atomicAdd(&colP[t * 16 + lq], colPs);
            }
        } else {
            // diagonal panel: self-mask only on the two tiles crossing this wave's rows
            const bool m0 = (J == I0);
            const bool m1 = (J == I0 + 16);
            if (m0) EPILOGUE(0, acc0, true, false) else EPILOGUE(0, acc0, false, false);
            if (m1) EPILOGUE(1, acc1, true, false) else EPILOGUE(1, acc1, false, false);
        }
    }
#undef EPILOGUE

    // row-side flush: reduce over lq (16 lanes) per quad, one atomic per row.
#pragma unroll
    for (int a = 0; a < 2; ++a) {
#pragma unroll
        for (int r = 0; r < 4; ++r) {
            float t = tacc[a][r], p = pacc[a][r];
#pragma unroll
            for (int off = 1; off < 16; off <<= 1) {
                t += __shfl_xor(t, off, 64);
                p += __shfl_xor(p, off, 64);
            }
            if (lq == 0) {
                const int row = I0 + a * 16 + quad * 4 + r;
                atomicAdd(&tot[row], t);
                atomicAdd(&pos[row], p);
            }
        }
    }

    // col-side flush: one pass, 128 cols.
    if (offdiag) {
        __syncthreads();
        if (threadIdx.x < 128) {
            atomicAdd(&tot[Jpanel + threadIdx.x], colT[threadIdx.x]);
            atomicAdd(&pos[Jpanel + threadIdx.x], colP[threadIdx.x]);
        }
    }
}

// ---------------- Kernel 3: row losses + per-class mean of means ----------------
__global__ __launch_bounds__(1024) void finalize_kernel(const float* __restrict__ pos,
                                                        const float* __restrict__ tot,
                                                        const int* __restrict__ lab,
                                                        float* __restrict__ out) {
    const int tid = threadIdx.x;
    float ls[NUM_CLASSES] = {0.f, 0.f, 0.f, 0.f};
    float lc[NUM_CLASSES] = {0.f, 0.f, 0.f, 0.f};
#pragma unroll
    for (int it = 0; it < N_PIX / 1024; ++it) {
        const int n = it * 1024 + tid;
        float rl = logf(tot[n] + 1e-6f) - logf(pos[n]);
        int c = lab[n];
#pragma unroll
        for (int k = 0; k < NUM_CLASSES; ++k) {
            if (c == k) {
                ls[k] += rl;
                lc[k] += 1.f;
            }
        }
    }
#pragma unroll
    for (int off = 1; off < 64; off <<= 1) {
#pragma unroll
        for (int k = 0; k < NUM_CLASSES; ++k) {
            ls[k] += __shfl_xor(ls[k], off, 64);
            lc[k] += __shfl_xor(lc[k], off, 64);
        }
    }
    __shared__ float ssum[16][NUM_CLASSES];
    __shared__ float scnt[16][NUM_CLASSES];
    const int wid = tid >> 6;
    if ((tid & 63) == 0) {
#pragma unroll
        for (int k = 0; k < NUM_CLASSES; ++k) {
            ssum[wid][k] = ls[k];
            scnt[wid][k] = lc[k];
        }
    }
    __syncthreads();
    if (tid == 0) {
        float acc = 0.f;
        int present = 0;
        for (int k = 0; k < NUM_CLASSES; ++k) {
            float s = 0.f, c = 0.f;
            for (int w = 0; w < 16; ++w) {
                s += ssum[w][k];
                c += scnt[w][k];
            }
            if (c > 0.f) {
                acc += s / c;
                present++;
            }
        }
        out[0] = acc / (float)(present > 0 ? present : 1);
    }
}

extern "C" void kernel_launch(void* const* d_in, const int* in_sizes, int n_in,
                              void* d_out, int out_size, void* d_ws, size_t ws_size,
                              hipStream_t stream) {
    const float* emb = (const float*)d_in[0];  // [2,128,64,64] fp32
    const int* lab = (const int*)d_in[1];      // [2,64,64] int32
    float* out = (float*)d_out;

    unsigned short* ebfT = (unsigned short*)d_ws;            // [512 tiles][4][64][8] bf16 = 2 MiB
    float* pos = (float*)((char*)d_ws + N_PIX * C_DIM * 2);  // [8192] f32
    float* tot = pos + N_PIX;                                // [8192] f32 (contiguous)

    normscale_kernel<<<N_PIX / 16, 256, 0, stream>>>(emb, ebfT, pos);

    dim3 grid(64, 33);  // triangular panel-pair cover; 2080 active blocks
    pairwise_kernel<<<grid, 256, 0, stream>>>(ebfT, lab, pos, tot);

    finalize_kernel<<<1, 1024, 0, stream>>>(pos, tot, lab, out);
}

// Round 9
// 95.257 us; speedup vs baseline: 1.2395x; 1.2395x over previous
//
#include <hip/hip_runtime.h>
#include <hip/hip_bf16.h>

#define N_PIX 8192
#define C_DIM 128
#define HW 4096
// exp(dot/0.1) = exp2(dot * 14.42695...); fold sqrt of that into each vector.
#define PRESCALE 3.7982825f  // sqrt(log2(e)/0.1)
#define NUM_CLASSES 4

typedef __attribute__((ext_vector_type(8))) short short8;   // 8 x bf16 (4 VGPRs)
typedef __attribute__((ext_vector_type(4))) float float4v;  // 4 x f32 acc

// Fragment-linear layout (R7 win): ebfT[((T*4 + s)*64 + lane)*8 + j] = e[T*16 + lq][s*32 + quad*8 + j],
// lane = quad*16 + lq. Fragment load = base + lane*16B: one coalesced 1KB dwordx4.

// ---------------- Kernel 1: L2-normalize + prescale + bf16 cast into ebfT; zero pos/tot ----------------
__global__ __launch_bounds__(256) void normscale_kernel(const float* __restrict__ emb,
                                                        unsigned short* __restrict__ ebfT,
                                                        float* __restrict__ pz) {
    const int tid = threadIdx.x;
    const int p16 = tid & 15;   // pixel within tile (lq)
    const int g = tid >> 4;     // channel group 0..15 (8 channels each)
    const int n = blockIdx.x * 16 + p16;
    const int b = n >> 12;
    const int hw = n & (HW - 1);
    const float* base = emb + b * (C_DIM * HW) + hw;

    float v[8];
    float ss = 0.f;
#pragma unroll
    for (int i = 0; i < 8; ++i) {
        v[i] = base[(g * 8 + i) * HW];
        ss += v[i] * v[i];
    }
    ss += __shfl_xor(ss, 16, 64);
    ss += __shfl_xor(ss, 32, 64);
    __shared__ float red[4][16];
    const int wv = tid >> 6;
    if ((tid & 63) < 16) red[wv][p16] = ss;
    __syncthreads();
    float tot = red[0][p16] + red[1][p16] + red[2][p16] + red[3][p16];
    float inv = PRESCALE / fmaxf(sqrtf(tot), 1e-12f);

    unsigned short us[8];
#pragma unroll
    for (int i = 0; i < 8; ++i) {
        __hip_bfloat16 h = __float2bfloat16(v[i] * inv);
        us[i] = *reinterpret_cast<unsigned short*>(&h);
    }
    const int s = g >> 2, quad = g & 3;
    unsigned short* dst = ebfT + (((blockIdx.x * 4 + s) * 64 + quad * 16 + p16) << 3);
    *reinterpret_cast<short8*>(dst) = *reinterpret_cast<short8*>(us);

    if (blockIdx.x < 64) pz[blockIdx.x * 256 + tid] = 0.f;
}

// ---------------- Kernel 2: symmetric fused S = e e^T, exp2, row+col sums ----------------
// Grid (64, 32): bi = I-panel (128 rows), d = blockIdx.y+1 in 1..32; jp = (bi+d)%64.
// d=1..31 covers each unordered off-diag panel pair once; d=32 double-covers -> bi>=32 culled.
// Phase 1 (all blocks): off-diag pair, SINGLE code path, no masking; each ex(i,j)
//   feeds row-side regs AND col-side per-tile global atomics (quad-reduced, per wave).
// Phase 2 (d==1 blocks only): diagonal panel bi, separate sequential loop, self-mask,
//   row-side only (accumulates into the same tacc/pacc; row flush at end covers both).
// Lessons: (256,4) not (256,8) [R3]; plain cached loads [R5]; macros, constant-indexed
// arrays, NO lambdas [R6]; ONE code path inside any tile loop [R8: dual-path loop body
// -> scratch demotion, VGPR=64 + WRITE 104MB signature].
__global__ __launch_bounds__(256, 4) void pairwise_kernel(const unsigned short* __restrict__ ebfT,
                                                          const int* __restrict__ lab,
                                                          float* __restrict__ pos,
                                                          float* __restrict__ tot) {
    const int bi = blockIdx.x;
    const int d = blockIdx.y + 1;          // 1..32
    if (d == 32 && bi >= 32) return;       // wrap double-cover cull (block-uniform)
    const int jp = (bi + d) & 63;
    const int Ipanel = bi << 7;
    const int Jpanel = jp << 7;

    const int wave = threadIdx.x >> 6;
    const int lane = threadIdx.x & 63;
    const int quad = lane >> 4;
    const int lq = lane & 15;

    const int I0 = Ipanel + wave * 32;

    // A fragments: tiles (I0>>4), (I0>>4)+1 — coalesced lane*16B loads.
    short8 afrag[2][4];
#pragma unroll
    for (int a = 0; a < 2; ++a) {
        const unsigned short* ab = ebfT + ((((I0 >> 4) + a) * 4) * 64 + lane) * 8;
#pragma unroll
        for (int s = 0; s < 4; ++s)
            afrag[a][s] = *reinterpret_cast<const short8*>(ab + s * 512);
    }
    int lab_row[2][4];
#pragma unroll
    for (int a = 0; a < 2; ++a)
#pragma unroll
        for (int r = 0; r < 4; ++r) lab_row[a][r] = lab[I0 + a * 16 + quad * 4 + r];

    float tacc[2][4] = {};
    float pacc[2][4] = {};

    // ---- Phase 1: off-diagonal panel pair (no masking, row + col side) ----
    {
        const unsigned short* bbase = ebfT + ((Jpanel >> 4) * 4 * 64 + lane) * 8;
        for (int t = 0; t < 8; ++t) {
            const int lab_col = lab[Jpanel + t * 16 + lq];
            const unsigned short* bt = bbase + t * 2048;
            short8 bfrag[4];
#pragma unroll
            for (int s = 0; s < 4; ++s)
                bfrag[s] = *reinterpret_cast<const short8*>(bt + s * 512);

            float4v acc0 = {0.f, 0.f, 0.f, 0.f};
            float4v acc1 = {0.f, 0.f, 0.f, 0.f};
#pragma unroll
            for (int s = 0; s < 4; ++s) {
                acc0 = __builtin_amdgcn_mfma_f32_16x16x32_bf16(afrag[0][s], bfrag[s], acc0, 0, 0, 0);
                acc1 = __builtin_amdgcn_mfma_f32_16x16x32_bf16(afrag[1][s], bfrag[s], acc1, 0, 0, 0);
            }

            float colTs = 0.f, colPs = 0.f;
#pragma unroll
            for (int r = 0; r < 4; ++r) {
                float ex = __builtin_amdgcn_exp2f(acc0[r]);
                tacc[0][r] += ex;
                float pxe = (lab_row[0][r] == lab_col) ? ex : 0.f;
                pacc[0][r] += pxe;
                colTs += ex;
                colPs += pxe;
            }
#pragma unroll
            for (int r = 0; r < 4; ++r) {
                float ex = __builtin_amdgcn_exp2f(acc1[r]);
                tacc[1][r] += ex;
                float pxe = (lab_row[1][r] == lab_col) ? ex : 0.f;
                pacc[1][r] += pxe;
                colTs += ex;
                colPs += pxe;
            }
            // col-side: this wave's 32-row partial for col = Jpanel + t*16 + lq
            colTs += __shfl_xor(colTs, 16, 64);
            colTs += __shfl_xor(colTs, 32, 64);
            colPs += __shfl_xor(colPs, 16, 64);
            colPs += __shfl_xor(colPs, 32, 64);
            if (quad == 0) {
                atomicAdd(&tot[Jpanel + t * 16 + lq], colTs);
                atomicAdd(&pos[Jpanel + t * 16 + lq], colPs);
            }
        }
    }

    // ---- Phase 2 (d==1 blocks only): diagonal panel bi, self-masked, row-side only ----
#define EPILOGUE(A, ACC, MASKED)                                            \
    {                                                                       \
        _Pragma("unroll") for (int r = 0; r < 4; ++r) {                     \
            float ex = __builtin_amdgcn_exp2f(ACC[r]);                      \
            if (MASKED) ex = (lq == quad * 4 + r) ? 0.f : ex;               \
            tacc[A][r] += ex;                                               \
            pacc[A][r] += (lab_row[A][r] == lab_col) ? ex : 0.f;            \
        }                                                                   \
    }
    if (d == 1) {
        const unsigned short* bbase = ebfT + ((Ipanel >> 4) * 4 * 64 + lane) * 8;
        for (int t = 0; t < 8; ++t) {
            const int J = Ipanel + t * 16;
            const int lab_col = lab[J + lq];
            const unsigned short* bt = bbase + t * 2048;
            short8 bfrag[4];
#pragma unroll
            for (int s = 0; s < 4; ++s)
                bfrag[s] = *reinterpret_cast<const short8*>(bt + s * 512);

            float4v acc0 = {0.f, 0.f, 0.f, 0.f};
            float4v acc1 = {0.f, 0.f, 0.f, 0.f};
#pragma unroll
            for (int s = 0; s < 4; ++s) {
                acc0 = __builtin_amdgcn_mfma_f32_16x16x32_bf16(afrag[0][s], bfrag[s], acc0, 0, 0, 0);
                acc1 = __builtin_amdgcn_mfma_f32_16x16x32_bf16(afrag[1][s], bfrag[s], acc1, 0, 0, 0);
            }
            if (J == I0) EPILOGUE(0, acc0, true) else EPILOGUE(0, acc0, false);
            if (J == I0 + 16) EPILOGUE(1, acc1, true) else EPILOGUE(1, acc1, false);
        }
    }
#undef EPILOGUE

    // ---- Row-side flush (covers phase 1 + phase 2) ----
#pragma unroll
    for (int a = 0; a < 2; ++a) {
#pragma unroll
        for (int r = 0; r < 4; ++r) {
            float t = tacc[a][r], p = pacc[a][r];
#pragma unroll
            for (int off = 1; off < 16; off <<= 1) {
                t += __shfl_xor(t, off, 64);
                p += __shfl_xor(p, off, 64);
            }
            if (lq == 0) {
                const int row = I0 + a * 16 + quad * 4 + r;
                atomicAdd(&tot[row], t);
                atomicAdd(&pos[row], p);
            }
        }
    }
}

// ---------------- Kernel 3: row losses + per-class mean of means ----------------
__global__ __launch_bounds__(1024) void finalize_kernel(const float* __restrict__ pos,
                                                        const float* __restrict__ tot,
                                                        const int* __restrict__ lab,
                                                        float* __restrict__ out) {
    const int tid = threadIdx.x;
    float ls[NUM_CLASSES] = {0.f, 0.f, 0.f, 0.f};
    float lc[NUM_CLASSES] = {0.f, 0.f, 0.f, 0.f};
#pragma unroll
    for (int it = 0; it < N_PIX / 1024; ++it) {
        const int n = it * 1024 + tid;
        float rl = logf(tot[n] + 1e-6f) - logf(pos[n]);
        int c = lab[n];
#pragma unroll
        for (int k = 0; k < NUM_CLASSES; ++k) {
            if (c == k) {
                ls[k] += rl;
                lc[k] += 1.f;
            }
        }
    }
#pragma unroll
    for (int off = 1; off < 64; off <<= 1) {
#pragma unroll
        for (int k = 0; k < NUM_CLASSES; ++k) {
            ls[k] += __shfl_xor(ls[k], off, 64);
            lc[k] += __shfl_xor(lc[k], off, 64);
        }
    }
    __shared__ float ssum[16][NUM_CLASSES];
    __shared__ float scnt[16][NUM_CLASSES];
    const int wid = tid >> 6;
    if ((tid & 63) == 0) {
#pragma unroll
        for (int k = 0; k < NUM_CLASSES; ++k) {
            ssum[wid][k] = ls[k];
            scnt[wid][k] = lc[k];
        }
    }
    __syncthreads();
    if (tid == 0) {
        float acc = 0.f;
        int present = 0;
        for (int k = 0; k < NUM_CLASSES; ++k) {
            float s = 0.f, c = 0.f;
            for (int w = 0; w < 16; ++w) {
                s += ssum[w][k];
                c += scnt[w][k];
            }
            if (c > 0.f) {
                acc += s / c;
                present++;
            }
        }
        out[0] = acc / (float)(present > 0 ? present : 1);
    }
}

extern "C" void kernel_launch(void* const* d_in, const int* in_sizes, int n_in,
                              void* d_out, int out_size, void* d_ws, size_t ws_size,
                              hipStream_t stream) {
    const float* emb = (const float*)d_in[0];  // [2,128,64,64] fp32
    const int* lab = (const int*)d_in[1];      // [2,64,64] int32
    float* out = (float*)d_out;

    unsigned short* ebfT = (unsigned short*)d_ws;            // [512 tiles][4][64][8] bf16 = 2 MiB
    float* pos = (float*)((char*)d_ws + N_PIX * C_DIM * 2);  // [8192] f32
    float* tot = pos + N_PIX;                                // [8192] f32 (contiguous)

    normscale_kernel<<<N_PIX / 16, 256, 0, stream>>>(emb, ebfT, pos);

    dim3 grid(64, 32);  // symmetric panel-pair cover; 2016 active + 64 diag-carrying blocks
    pairwise_kernel<<<grid, 256, 0, stream>>>(ebfT, lab, pos, tot);

    finalize_kernel<<<1, 1024, 0, stream>>>(pos, tot, lab, out);
}